// Round 8
// baseline (451.132 us; speedup 1.0000x reference)
//
#include <hip/hip_runtime.h>
#include <math.h>

#define B 2
#define S 1024
#define E 2048
#define H 16
#define HD 128
#define ROT 64
#define EPSN 1e-12f

using half8 = __attribute__((ext_vector_type(8))) _Float16;
using half4 = __attribute__((ext_vector_type(4))) _Float16;
using half2 = __attribute__((ext_vector_type(2))) _Float16;
using f32x4 = __attribute__((ext_vector_type(4))) float;

// async global->LDS, 16B per lane; LDS dest = wave-uniform base + lane*16
__device__ __forceinline__ void gl_lds16(const void* g, void* l) {
    __builtin_amdgcn_global_load_lds(
        (const __attribute__((address_space(1))) unsigned int*)g,
        (__attribute__((address_space(3))) unsigned int*)l, 16, 0, 0);
}

// ---------------------------------------------------------------------------
// Batched fp32 -> fp16: 5 tensors, each exactly B*S*E = E*E = 4M elements.
// ---------------------------------------------------------------------------
__global__ __launch_bounds__(256) void f2h5(const float* __restrict__ x0,
                                            const float* __restrict__ x1,
                                            const float* __restrict__ x2,
                                            const float* __restrict__ x3,
                                            const float* __restrict__ x4,
                                            _Float16* __restrict__ y0,
                                            _Float16* __restrict__ y1,
                                            _Float16* __restrict__ y2,
                                            _Float16* __restrict__ y3,
                                            _Float16* __restrict__ y4) {
    const float* xs[5] = {x0, x1, x2, x3, x4};
    _Float16*    ys[5] = {y0, y1, y2, y3, y4};
    const int t = blockIdx.y;
    const int i = blockIdx.x * 256 + threadIdx.x;
    float4 v = ((const float4*)xs[t])[i];
    half4 h;
    h[0] = (_Float16)v.x; h[1] = (_Float16)v.y;
    h[2] = (_Float16)v.z; h[3] = (_Float16)v.w;
    ((half4*)ys[t])[i] = h;
}

// ---------------------------------------------------------------------------
// Fused QKV NT-GEMM, fp16, global_load_lds, double-buffered BK=32.
// NEW (R8): 64m x 128n blocks, 2 waves -> 1536 blocks = 6 blocks/CU,
// doubling the independent barrier domains per CU to hide the per-iter
// vmcnt drain (R7 showed 3 domains insufficient: MfmaUtil 19.5%).
// Wave tile 64x64 (16 MFMA per 8 ds_read_b128). blockIdx.z -> {wq,wk,wv}.
// LDS per buffer: [rb(16 rows)][kq 0..3][r 0..15] uint4, DMA lane = kq*16+r.
// A-frag: lane holds A[m=lane&15][k=(lane>>4)*8+j]; C/D: row=(lane>>4)*4+reg,
// col=lane&15 (verified rounds 2-7).
// ---------------------------------------------------------------------------
__global__ __launch_bounds__(128) void gemm_qkv(const _Float16* __restrict__ hs,
                                                const _Float16* __restrict__ wq,
                                                const _Float16* __restrict__ wk,
                                                const _Float16* __restrict__ wv,
                                                _Float16* __restrict__ qo,
                                                _Float16* __restrict__ ko,
                                                _Float16* __restrict__ vo) {
    __shared__ uint4 As_l[2][256];   // 2 x 4 KB: 4 row-blocks (64 m-rows)
    __shared__ uint4 Ws_l[2][512];   // 2 x 8 KB: 8 row-blocks (128 n-rows)
    const _Float16* Wp = (blockIdx.z == 0) ? wq : (blockIdx.z == 1) ? wk : wv;
    _Float16*       C  = (blockIdx.z == 0) ? qo : (blockIdx.z == 1) ? ko : vo;
    const int tid  = threadIdx.x;
    const int lane = tid & 63;
    const int w    = tid >> 6;        // 0..1
    const int wn   = w * 64;          // n-offset within head
    const int l15  = lane & 15;
    const int lq   = lane >> 4;
    const int r16  = lane & 15;       // staging row within 16-row block
    const int kq4  = lane >> 4;       // staging 16B k-chunk (0..3)
    const int mBase = blockIdx.y * 64;         // over B*S
    const int h     = blockIdx.x;              // head
    const int nBase = h * 128;

    f32x4 acc[4][4];
#pragma unroll
    for (int mt = 0; mt < 4; ++mt)
#pragma unroll
        for (int nt = 0; nt < 4; ++nt)
            acc[mt][nt] = (f32x4){0.f, 0.f, 0.f, 0.f};

    auto stage = [&](int bf, int k0) {
#pragma unroll
        for (int i = 0; i < 2; ++i) {
            int rb = w * 2 + i;                // A row-blocks 0..3
            gl_lds16(&hs[(size_t)(mBase + rb * 16 + r16) * E + k0 + kq4 * 8],
                     &As_l[bf][rb * 64]);
        }
#pragma unroll
        for (int i = 0; i < 4; ++i) {
            int rb = w * 4 + i;                // W row-blocks 0..7
            gl_lds16(&Wp[(size_t)(nBase + rb * 16 + r16) * E + k0 + kq4 * 8],
                     &Ws_l[bf][rb * 64]);
        }
    };

    stage(0, 0);                                // prologue
    const int nIter = E / 32;                   // 64
    for (int it = 0; it < nIter; ++it) {
        __syncthreads();   // drains vmcnt -> buf[it&1] ready; prev reads done
        if (it + 1 < nIter) stage((it + 1) & 1, (it + 1) * 32);

        const int cur = it & 1;
        half8 af[4], wf[4];
#pragma unroll
        for (int t = 0; t < 4; ++t) {
            af[t] = *(const half8*)&As_l[cur][t * 64 + lq * 16 + l15];
            wf[t] = *(const half8*)&Ws_l[cur][(w * 4 + t) * 64 + lq * 16 + l15];
        }
#pragma unroll
        for (int mt = 0; mt < 4; ++mt)
#pragma unroll
            for (int nt = 0; nt < 4; ++nt)
                acc[mt][nt] = __builtin_amdgcn_mfma_f32_16x16x32_f16(
                    af[mt], wf[nt], acc[mt][nt], 0, 0, 0);
    }

    // write (b,h,s,d) fp16
#pragma unroll
    for (int mt = 0; mt < 4; ++mt)
#pragma unroll
        for (int nt = 0; nt < 4; ++nt)
#pragma unroll
            for (int r = 0; r < 4; ++r) {
                int row = mBase + mt * 16 + lq * 4 + r;   // global s in B*S
                int d   = wn + nt * 16 + l15;
                int b = row >> 10, s = row & (S - 1);
                C[(((size_t)b * H + h) * S + s) * HD + d] = (_Float16)acc[mt][nt][r];
            }
}

// ---------------------------------------------------------------------------
// Out-projection NT-GEMM, fp16, global_load_lds, dbuf BK=32.
// NEW (R8): single-wave 64x64 blocks -> 1024 blocks (~4+/CU); __syncthreads
// in a 1-wave block compiles to a bare waitcnt (no s_barrier).
// ---------------------------------------------------------------------------
__global__ __launch_bounds__(64) void gemm_out(const _Float16* __restrict__ A,
                                               const _Float16* __restrict__ Wp,
                                               float* __restrict__ C) {
    __shared__ uint4 As_l[2][256];   // 2 x 4 KB (4 row-blocks)
    __shared__ uint4 Ws_l[2][256];   // 2 x 4 KB
    const int lane = threadIdx.x & 63;
    const int l15  = lane & 15;
    const int lq   = lane >> 4;
    const int r16  = lane & 15;
    const int kq4  = lane >> 4;
    const int mBase = blockIdx.y * 64;
    const int nBase = blockIdx.x * 64;

    f32x4 acc[4][4];
#pragma unroll
    for (int mt = 0; mt < 4; ++mt)
#pragma unroll
        for (int nt = 0; nt < 4; ++nt)
            acc[mt][nt] = (f32x4){0.f, 0.f, 0.f, 0.f};

    auto stage = [&](int bf, int k0) {
#pragma unroll
        for (int rb = 0; rb < 4; ++rb) {
            gl_lds16(&A[(size_t)(mBase + rb * 16 + r16) * E + k0 + kq4 * 8],
                     &As_l[bf][rb * 64]);
            gl_lds16(&Wp[(size_t)(nBase + rb * 16 + r16) * E + k0 + kq4 * 8],
                     &Ws_l[bf][rb * 64]);
        }
    };

    stage(0, 0);
    const int nIter = E / 32;                   // 64
    for (int it = 0; it < nIter; ++it) {
        __syncthreads();
        if (it + 1 < nIter) stage((it + 1) & 1, (it + 1) * 32);

        const int cur = it & 1;
        half8 af[4], wf[4];
#pragma unroll
        for (int t = 0; t < 4; ++t) {
            af[t] = *(const half8*)&As_l[cur][t * 64 + lq * 16 + l15];
            wf[t] = *(const half8*)&Ws_l[cur][t * 64 + lq * 16 + l15];
        }
#pragma unroll
        for (int mt = 0; mt < 4; ++mt)
#pragma unroll
            for (int nt = 0; nt < 4; ++nt)
                acc[mt][nt] = __builtin_amdgcn_mfma_f32_16x16x32_f16(
                    af[mt], wf[nt], acc[mt][nt], 0, 0, 0);
    }

#pragma unroll
    for (int mt = 0; mt < 4; ++mt)
#pragma unroll
        for (int nt = 0; nt < 4; ++nt)
#pragma unroll
            for (int r = 0; r < 4; ++r) {
                int row = mBase + mt * 16 + lq * 4 + r;
                int col = nBase + nt * 16 + l15;
                C[(size_t)row * E + col] = acc[mt][nt][r];
            }
}

// ---------------------------------------------------------------------------
// Rotary + L2 normalize + mask, in-place on fp16 (b,h,s,d).
// ---------------------------------------------------------------------------
__global__ __launch_bounds__(256) void rotary_norm(_Float16* __restrict__ qh,
                                                   _Float16* __restrict__ kh,
                                                   const float* __restrict__ am,
                                                   const int* __restrict__ pos) {
    const int wave = threadIdx.x >> 6;
    const int lane = threadIdx.x & 63;
    const int item = blockIdx.x * 4 + wave;      // < B*H*S
    const int b = item / (H * S);
    const int h = (item / S) % H;
    const int s = item % S;

    const float p = (float)pos[b * S + s];
    float co = 1.f, si = 0.f;
    if (lane < 32) {
        float ang = p * expf(-0.28782313662425574f * (float)lane); // ln(10000)/32
        sincosf(ang, &si, &co);
    }
    const float valid = (am[b * S + s] == 0.f) ? 1.f : 0.f;
    const size_t base = ((size_t)(b * H + h) * S + s) * HD;

    _Float16* bufs[2] = {qh, kh};
#pragma unroll
    for (int a = 0; a < 2; ++a) {
        _Float16* ptr = bufs[a];
        half2 xin = *(const half2*)&ptr[base + 2 * lane];
        float x0 = (float)xin[0], x1 = (float)xin[1];
        float y0, y1;
        if (lane < 32) {
            y0 = x0 * co - x1 * si;
            y1 = x1 * co + x0 * si;
        } else {
            y0 = x0;
            y1 = x1;
        }
        float ss = y0 * y0 + y1 * y1;
#pragma unroll
        for (int off = 32; off > 0; off >>= 1)
            ss += __shfl_xor(ss, off);
        float scale = valid / fmaxf(sqrtf(ss), EPSN);
        half2 xo;
        xo[0] = (_Float16)(y0 * scale);
        xo[1] = (_Float16)(y1 * scale);
        *(half2*)&ptr[base + 2 * lane] = xo;
    }
}

// ---------------------------------------------------------------------------
// vprep (computes mask-prefix counts via wave scan):
// v (b,h,s,d) fp16 -> scaled V^T (b,h,d,s) fp16,
// scale = mask / max(counts^sigmoid(nc[h]), 1).
// ---------------------------------------------------------------------------
__global__ __launch_bounds__(256) void vprep(const _Float16* __restrict__ v,
                                             _Float16* __restrict__ vt,
                                             const float* __restrict__ am,
                                             const float* __restrict__ nc) {
    __shared__ _Float16 T[HD][72];     // [d][s] pad 8
    __shared__ float sscale[64];
    const int bh = blockIdx.y;
    const int b = bh >> 4, h = bh & 15;
    const int s0 = blockIdx.x * 64;
    const int tid = threadIdx.x;

    if (tid < 64) {
        const int lane = tid;
        float basec = 0.f;
        for (int j0 = 0; j0 < s0; j0 += 64) {
            float z = (am[b * S + j0 + lane] == 0.f) ? 1.f : 0.f;
#pragma unroll
            for (int off = 32; off > 0; off >>= 1)
                z += __shfl_xor(z, off);
            basec += z;                        // wave-uniform
        }
        float zown = (am[b * S + s0 + lane] == 0.f) ? 1.f : 0.f;
        float sc = zown;                       // inclusive wave scan
#pragma unroll
        for (int off = 1; off < 64; off <<= 1) {
            float u = __shfl_up(sc, off);
            if (lane >= off) sc += u;
        }
        float cntv = basec + sc;
        float sig = 1.f / (1.f + expf(-nc[h]));
        float denom = fmaxf(powf(cntv, sig), 1.f);
        sscale[lane] = zown / denom;
    }
    __syncthreads();

#pragma unroll
    for (int j = 0; j < 4; ++j) {
        int f = tid + j * 256;
        int s = f >> 4, c8 = f & 15;
        half8 x = *(const half8*)&v[((size_t)bh * S + s0 + s) * HD + c8 * 8];
        float sc = sscale[s];
#pragma unroll
        for (int i = 0; i < 8; ++i)
            T[c8 * 8 + i][s] = (_Float16)((float)x[i] * sc);
    }
    __syncthreads();

#pragma unroll
    for (int j = 0; j < 4; ++j) {
        int f = tid + j * 256;
        int d = f >> 3, c8 = f & 7;
        *(uint4*)&vt[((size_t)bh * HD + d) * S + s0 + c8 * 8] =
            *(const uint4*)&T[d][c8 * 8];
    }
}

// ---------------------------------------------------------------------------
// MFMA attention with register prefetch of the next K/V chunk.
// qh,kh: (b,h,s,d); vt: (b,h,d,s); o: (b,s,E) fp16.
// ---------------------------------------------------------------------------
__global__ __launch_bounds__(256) void attn_mfma(const _Float16* __restrict__ qh,
                                                 const _Float16* __restrict__ kh,
                                                 const _Float16* __restrict__ vt,
                                                 _Float16* __restrict__ o) {
    __shared__ _Float16 Ks[64][136];   // [key][d], +8 pad
    __shared__ _Float16 Vs[HD][72];    // [d][key], +8 pad
    __shared__ _Float16 Ps[64][72];    // [q][key], +8 pad

    const int qt = (int)gridDim.x - 1 - (int)blockIdx.x;   // heavy first
    const int bh = blockIdx.y;
    const int b = bh >> 4, h = bh & 15;
    const int tid = threadIdx.x;
    const int lane = tid & 63;
    const int w = tid >> 6;
    const int l15 = lane & 15;
    const int lq = lane >> 4;
    const int qBase = qt * 64;
    const size_t sd_base = (size_t)bh * S * HD;

    // Q A-frags in registers
    half8 qf[4];
#pragma unroll
    for (int ks = 0; ks < 4; ++ks)
        qf[ks] = *(const half8*)&qh[sd_base + (size_t)(qBase + w * 16 + l15) * HD +
                                    ks * 32 + lq * 8];

    f32x4 oacc[8];
#pragma unroll
    for (int dt = 0; dt < 8; ++dt)
        oacc[dt] = (f32x4){0.f, 0.f, 0.f, 0.f};

    const int nkc = qt + 1;
    uint4 pk[4], pv[4];
    // prefetch chunk 0
#pragma unroll
    for (int j = 0; j < 4; ++j) {
        int f = tid + j * 256;
        int rK = f >> 4, c8K = f & 15;
        int rV = f >> 3, c8V = f & 7;
        pk[j] = *(const uint4*)&kh[sd_base + (size_t)rK * HD + c8K * 8];
        pv[j] = *(const uint4*)&vt[sd_base + (size_t)rV * S + c8V * 8];
    }

    for (int kc = 0; kc < nkc; ++kc) {
        __syncthreads();   // prev-iter Ks/Vs reads complete
#pragma unroll
        for (int j = 0; j < 4; ++j) {
            int f = tid + j * 256;
            int rK = f >> 4, c8K = f & 15;
            int rV = f >> 3, c8V = f & 7;
            *(uint4*)&Ks[rK][c8K * 8] = pk[j];
            *(uint4*)&Vs[rV][c8V * 8] = pv[j];
        }
        __syncthreads();

        // issue next chunk's loads; they fly during compute below
        if (kc + 1 < nkc) {
            const int kB = (kc + 1) * 64;
#pragma unroll
            for (int j = 0; j < 4; ++j) {
                int f = tid + j * 256;
                int rK = f >> 4, c8K = f & 15;
                int rV = f >> 3, c8V = f & 7;
                pk[j] = *(const uint4*)&kh[sd_base + (size_t)(kB + rK) * HD + c8K * 8];
                pv[j] = *(const uint4*)&vt[sd_base + (size_t)rV * S + kB + c8V * 8];
            }
        }

        const int kBase = kc * 64;
        // QK^T: 4 key-tiles x 4 k-steps
        f32x4 sacc[4];
#pragma unroll
        for (int nt = 0; nt < 4; ++nt)
            sacc[nt] = (f32x4){0.f, 0.f, 0.f, 0.f};
#pragma unroll
        for (int nt = 0; nt < 4; ++nt)
#pragma unroll
            for (int ks = 0; ks < 4; ++ks) {
                half8 kf = *(const half8*)&Ks[nt * 16 + l15][ks * 32 + lq * 8];
                sacc[nt] = __builtin_amdgcn_mfma_f32_16x16x32_f16(qf[ks], kf,
                                                                  sacc[nt], 0, 0, 0);
            }

        // causal mask + P to LDS (C-layout write, wave-local rows)
#pragma unroll
        for (int nt = 0; nt < 4; ++nt)
#pragma unroll
            for (int r = 0; r < 4; ++r) {
                int qg = qBase + w * 16 + lq * 4 + r;
                int kg = kBase + nt * 16 + l15;
                float sv = (kg <= qg) ? sacc[nt][r] : 0.f;
                Ps[w * 16 + lq * 4 + r][nt * 16 + l15] = (_Float16)sv;
            }

        // PV: A-frags from Ps (wave-local), B-frags from Vs rows (= d)
        half8 pf[2];
        pf[0] = *(const half8*)&Ps[w * 16 + l15][lq * 8];
        pf[1] = *(const half8*)&Ps[w * 16 + l15][32 + lq * 8];
#pragma unroll
        for (int dt = 0; dt < 8; ++dt)
#pragma unroll
            for (int ks = 0; ks < 2; ++ks) {
                half8 vf = *(const half8*)&Vs[dt * 16 + l15][ks * 32 + lq * 8];
                oacc[dt] = __builtin_amdgcn_mfma_f32_16x16x32_f16(pf[ks], vf,
                                                                  oacc[dt], 0, 0, 0);
            }
    }

    // write O (b,s,E) fp16
#pragma unroll
    for (int dt = 0; dt < 8; ++dt)
#pragma unroll
        for (int r = 0; r < 4; ++r) {
            size_t off = (size_t)(b * S + qBase + w * 16 + lq * 4 + r) * E +
                         h * HD + dt * 16 + l15;
            o[off] = (_Float16)oacc[dt][r];
        }
}

// ---------------------------------------------------------------------------
extern "C" void kernel_launch(void* const* d_in, const int* in_sizes, int n_in,
                              void* d_out, int out_size, void* d_ws, size_t ws_size,
                              hipStream_t stream) {
    (void)in_sizes; (void)n_in; (void)out_size; (void)ws_size;
    const float* hs = (const float*)d_in[0];
    const float* wq = (const float*)d_in[1];
    const float* wk = (const float*)d_in[2];
    const float* wv = (const float*)d_in[3];
    const float* wo = (const float*)d_in[4];
    const float* nc = (const float*)d_in[5];
    const float* am = (const float*)d_in[6];
    const int*  pos = (const int*)d_in[7];
    float* out = (float*)d_out;

    const size_t act = (size_t)B * S * E;           // 4,194,304 (== E*E)
    _Float16* hsb = (_Float16*)d_ws;                // fp16 copies
    _Float16* wqb = hsb + act;
    _Float16* wkb = wqb + act;
    _Float16* wvb = wkb + act;
    _Float16* wob = wvb + act;
    _Float16* qhh = wob + act;                      // (b,h,s,d)
    _Float16* khh = qhh + act;
    _Float16* vhh = khh + act;                      // (b,h,s,d)
    _Float16* vtt = vhh + act;                      // (b,h,d,s)
    _Float16* abb = vtt + act;                      // attn out (b,s,E)
    // total ws: 10 * 8.39MB ~= 84 MB

    f2h5<<<dim3((int)(act / 4 / 256), 5), 256, 0, stream>>>(
        hs, wq, wk, wv, wo, hsb, wqb, wkb, wvb, wob);

    dim3 qkvgrid(H, (B * S) / 64, 3);               // 16 x 32 x 3 = 1536 blocks
    gemm_qkv<<<qkvgrid, 128, 0, stream>>>(hsb, wqb, wkb, wvb, qhh, khh, vhh);

    rotary_norm<<<(B * H * S) / 4, 256, 0, stream>>>(qhh, khh, am, pos);
    vprep<<<dim3(S / 64, B * H), 256, 0, stream>>>(vhh, vtt, am, nc);

    attn_mfma<<<dim3(S / 64, B * H), 256, 0, stream>>>(qhh, khh, vtt, abb);

    gemm_out<<<dim3(E / 64, (B * S) / 64), 64, 0, stream>>>(abb, wob, out);
}